// Round 2
// baseline (250.746 us; speedup 1.0000x reference)
//
#include <hip/hip_runtime.h>
#include <math.h>

constexpr int Bc = 64;      // batch
constexpr int Vc = 8000;    // vocab
constexpr int Kc = 50;      // topics

// ws float-offsets
#define WS_NSUM   0      // 50  exp_n colsum
#define WS_SSUM   50     // 50  exp_s colsum
#define WS_GSR    100    // 50  gamma_sr_sum (atomic)
#define WS_QZ     150    // exp_q_z acc (atomic f32)
#define WS_BATCHC 151    // batch_C (atomic int)
#define WS_SCNT   152    // seed-word count S (atomic int)
#define WS_SSNEW  160    // 50  exp_s_sum_new
#define WS_PM     256    // 3200 temp_m pre-theta accum (atomic f32)
#define WS_SC     4096               // [v][k] sv*st*pi
#define WS_N1     (WS_SC + Vc*Kc)    // [v][k] sv*rt*(1-pi)
#define WS_N2     (WS_N1 + Vc*Kc)    // [v][k] (1-sv)*rt
#define WS_SW     (WS_N2 + Vc*Kc)    // [v]    seed_word flag
#define WS_BT     (WS_SW + Vc)       // [v][b] bow transposed (int)
#define WS_IS     (WS_BT + Bc*Vc)    // [v][b] mask/(S+eps)
#define WS_IR     (WS_IS + Bc*Vc)    // [v][b] mask/(R+eps)
#define WS_END    (WS_IR + Bc*Vc)

// ---------------- k1: column sums, batch_C, seed-word count + flags ----------
__global__ __launch_bounds__(256) void k1_pre(const int* __restrict__ bow,
    const float* __restrict__ seeds, const float* __restrict__ exp_n,
    const float* __restrict__ exp_s, float* __restrict__ ws, float* __restrict__ sw)
{
    __shared__ float redf[256];
    __shared__ int   redi[256];
    const int t = threadIdx.x;
    const int blk = blockIdx.x;
    if (blk < Kc) {
        float sn = 0.f, ss = 0.f;
        for (int v = t; v < Vc; v += 256) {
            sn += exp_n[v*Kc + blk];
            ss += exp_s[v*Kc + blk];
        }
        redf[t] = sn; __syncthreads();
        for (int s = 128; s > 0; s >>= 1) { if (t < s) redf[t] += redf[t+s]; __syncthreads(); }
        if (t == 0) ws[blk] = redf[0];
        __syncthreads();
        redf[t] = ss; __syncthreads();
        for (int s = 128; s > 0; s >>= 1) { if (t < s) redf[t] += redf[t+s]; __syncthreads(); }
        if (t == 0) ws[Kc + blk] = redf[0];
    } else if (blk < Kc + 32) {
        int acc = 0;
        for (int i = (blk - Kc)*256 + t; i < Bc*Vc; i += 32*256) acc += bow[i];
        redi[t] = acc; __syncthreads();
        for (int s = 128; s > 0; s >>= 1) { if (t < s) redi[t] += redi[t+s]; __syncthreads(); }
        if (t == 0) atomicAdd((int*)ws + WS_BATCHC, redi[0]);
    } else {
        int cnt = 0;
        for (int v = (blk - Kc - 32)*256 + t; v < Vc; v += 8*256) {
            const float* row = seeds + v*Kc;
            int any = 0;
            for (int k = 0; k < Kc; ++k) any |= (row[k] != 0.f);
            cnt += any;
            if (sw) sw[v] = any ? 1.f : 0.f;
        }
        redi[t] = cnt; __syncthreads();
        for (int s = 128; s > 0; s >>= 1) { if (t < s) redi[t] += redi[t+s]; __syncthreads(); }
        if (t == 0) atomicAdd((int*)ws + WS_SCNT, redi[0]);
    }
}

// ---------------- A0: transpose bow [b][v] -> [v][b] -------------------------
__global__ __launch_bounds__(256) void kA0(const int* __restrict__ bow,
                                           int* __restrict__ bow_t)
{
    int i = blockIdx.x*256 + threadIdx.x;
    if (i < Bc*Vc) {
        int b = i / Vc, v = i - b*Vc;
        bow_t[v*Bc + b] = bow[i];
    }
}

// ---------------- A1: per-(v,k) coefficient arrays ---------------------------
__global__ __launch_bounds__(256) void kA1(const float* __restrict__ seeds,
    const float* __restrict__ exp_n, const float* __restrict__ exp_s,
    const float* __restrict__ pi, float* __restrict__ ws)
{
    int i = blockIdx.x*256 + threadIdx.x;
    if (i >= Vc*Kc) return;
    int k = i % Kc;
    float Sf = (float)(((const int*)ws)[WS_SCNT]);
    float st = (0.1f + exp_s[i]) / (0.1f*Sf + ws[WS_SSUM + k]);     // seed_topic_term
    float rt = (0.1f + exp_n[i]) / (0.1f*(float)Vc + ws[WS_NSUM + k]); // reg_topic_term
    float sv = seeds[i];
    float pk = pi[k];
    ws[WS_SC + i] = sv*st*pk;            // sc
    ws[WS_N1 + i] = sv*rt*(1.f - pk);    // nc1
    ws[WS_N2 + i] = (1.f - sv)*rt;       // nc2
}

// ---------------- BD: per-(b,v) S,R -> invs/invr; temp_m pre-acc; qz ---------
// lanes = b, wave = v. Zero cross-lane ops in the hot loop.
__global__ __launch_bounds__(512) void kBD(const int* __restrict__ bidx,
    const float* __restrict__ exp_m, const float* __restrict__ pi,
    float* __restrict__ ws)
{
    __shared__ float th_lds[Bc*51];
    __shared__ float pm_lds[Bc*Kc];
    const int t = threadIdx.x;
    for (int i = t; i < Bc*Kc; i += 512) pm_lds[i] = 0.f;
    for (int i = t; i < Bc*Kc; i += 512) {
        int b = i / Kc, k = i - b*Kc;
        th_lds[b*51 + k] = exp_m[bidx[b]*Kc + k] + 0.1f;   // theta
    }
    __syncthreads();
    const int lane = t & 63;
    const int wid  = t >> 6;

    float th[Kc];
#pragma unroll
    for (int k = 0; k < Kc; ++k) th[k] = th_lds[lane*51 + k];

    const float* sc = ws + WS_SC;
    const float* n1 = ws + WS_N1;
    const float* n2 = ws + WS_N2;
    const float* swv = ws + WS_SW;
    const int* bow_t = (const int*)ws + WS_BT;
    float* invs = ws + WS_IS;
    float* invr = ws + WS_IR;

    float pm[Kc];
#pragma unroll
    for (int k = 0; k < Kc; ++k) pm[k] = 0.f;
    float qz = 0.f;

    const int gw = blockIdx.x*8 + wid, nw = gridDim.x*8;
    for (int v = gw; v < Vc; v += nw) {
        const int vu = __builtin_amdgcn_readfirstlane(v);
        const float* scr = sc + vu*Kc;   // wave-uniform -> s_load rows
        const float* n1r = n1 + vu*Kc;
        const float* n2r = n2 + vu*Kc;
        const float sw  = swv[vu];
        const float bw  = (float)bow_t[vu*Bc + lane];   // coalesced

        float S = 0.f, R = 0.f;
#pragma unroll
        for (int k = 0; k < Kc; ++k) {
            S = fmaf(th[k], scr[k] + n1r[k], S);   // C = sc+nc1
            R = fmaf(th[k], n2r[k], R);            // D = nc2
        }
        const bool msk = bw > 0.f;
        const float is = msk ? 1.f/(S + 1e-6f) : 0.f;
        const float ir = msk ? 1.f/(R + 1e-6f) : 0.f;
        invs[vu*Bc + lane] = is;
        invr[vu*Bc + lane] = ir;

#pragma unroll
        for (int k = 0; k < Kc; ++k) {
            float pk = pi[k];
            float n1v = n1r[k], n2v = n2r[k];
            float ge = fmaf(pk, scr[k], n1v - pk*n1v);      // pi*sc + (1-pi)*nc1
            float gf = (sw != 0.f) ? (n2v - pk*n2v) : n2v;  // seed_word? (1-pi)*nc2 : nc2
            float t1 = fmaf(ge, is, gf*ir);
            float g  = th[k]*t1;                            // gamma[b,v,k]
            qz = fmaf(g, __logf(g + 1e-6f), qz);
            pm[k] = fmaf(bw, t1, pm[k]);                    // Σ_v bw*(g/th)
        }
    }

#pragma unroll
    for (int k = 0; k < Kc; ++k) atomicAdd(&pm_lds[lane*Kc + k], pm[k]);
#pragma unroll
    for (int off = 32; off; off >>= 1) qz += __shfl_xor(qz, off);
    if (lane == 0) atomicAdd(ws + WS_QZ, qz);
    __syncthreads();
    for (int i = t; i < Bc*Kc; i += 512) {
        atomicAdd(ws + WS_PM + i, pm_lds[i]);
    }
}

// ---------------- C: temp_n, temp_s, gamma_sr_sum ----------------------------
// lanes = k, wave = v; p/q/p2 rows via wave-uniform s_loads; theta from LDS.
__global__ __launch_bounds__(512) void kC(const int* __restrict__ bidx,
    const float* __restrict__ exp_m, float* __restrict__ ws,
    float* __restrict__ out)
{
    __shared__ float th_lds[Bc*51 + 16];
    const int t = threadIdx.x;
    for (int i = t; i < Bc*Kc; i += 512) {
        int b = i / Kc, k = i - b*Kc;
        th_lds[b*51 + k] = exp_m[bidx[b]*Kc + k] + 0.1f;
    }
    __syncthreads();
    const int lane = t & 63, wid = t >> 6;
    const float* sc = ws + WS_SC;
    const float* n1 = ws + WS_N1;
    const float* n2 = ws + WS_N2;
    const float* invs = ws + WS_IS;
    const float* invr = ws + WS_IR;
    const int* bow_t = (const int*)ws + WS_BT;
    float* out_n = out + Bc*Kc;
    float* out_s = out + Bc*Kc + Vc*Kc;

    float gacc = 0.f;
    const int gw = blockIdx.x*8 + wid, nw = gridDim.x*8;
    for (int v = gw; v < Vc; v += nw) {
        const int vu = __builtin_amdgcn_readfirstlane(v);
        const float* isr = invs + vu*Bc;   // wave-uniform rows -> s_load
        const float* irr = invr + vu*Bc;
        const int*   bwr = bow_t + vu*Bc;
        float PT = 0.f, QT = 0.f, P2 = 0.f;
#pragma unroll
        for (int b = 0; b < Bc; ++b) {
            float is = isr[b], ir = irr[b];
            float bwf = (float)bwr[b];
            float th = th_lds[b*51 + lane];
            PT = fmaf(bwf*is, th, PT);
            QT = fmaf(bwf*ir, th, QT);
            P2 = fmaf(is,     th, P2);
        }
        if (lane < Kc) {
            const int i = vu*Kc + lane;
            float n1v = n1[i], n2v = n2[i], scv = sc[i];
            out_n[i] = fmaf(n1v, PT, n2v*QT);   // temp_exp_n (staging)
            out_s[i] = scv*PT;                  // temp_exp_s (staging)
            gacc = fmaf(n1v, P2, gacc);         // gamma_sr_sum partial
        }
    }
    if (lane < Kc) atomicAdd(ws + WS_GSR + lane, gacc);
}

// ---------------- E: finalize all outputs ------------------------------------
__global__ __launch_bounds__(256) void k3_fin2(
    const float* __restrict__ exp_m, const float* __restrict__ exp_n,
    const float* __restrict__ exp_s, const int* __restrict__ bidx,
    const int* __restrict__ itern_p, float* __restrict__ out,
    float* __restrict__ ws)
{
    const int t = threadIdx.x, blk = blockIdx.x;
    int ii = itern_p[0];
    float itern = (ii >= 0 && ii < 1000000) ? (float)ii : __int_as_float(ii);
    const float rho = 1.f / powf(itern + 5.f, 0.9f);
    const float omr = 1.f - rho;
    const float bC  = (float)(((const int*)ws)[WS_BATCHC]);
    const float scale = 1e7f / bC;
    float* out_m = out;
    float* out_n = out + Bc*Kc;
    float* out_s = out + Bc*Kc + Vc*Kc;

    if (blk < Kc) {
        const int k = blk;
        float acc = 0.f;
        for (int v = t; v < Vc; v += 256) {
            int i = v*Kc + k;
            out_n[i] = omr*exp_n[i] + rho*scale*out_n[i];
            float snew = omr*exp_s[i] + rho*scale*out_s[i];
            out_s[i] = snew;
            acc += snew;
        }
        __shared__ float redf[256];
        redf[t] = acc; __syncthreads();
        for (int s = 128; s > 0; s >>= 1) { if (t < s) redf[t] += redf[t+s]; __syncthreads(); }
        if (t == 0) ws[WS_SSNEW + k] = redf[0];
    } else {
        for (int i = t; i < Bc*Kc; i += 256) {
            int b = i / Kc, k = i - b*Kc;
            float th = exp_m[bidx[b]*Kc + k] + 0.1f;
            out_m[i] = omr*(th - 0.1f) + rho*(th*ws[WS_PM + i]);
        }
        if (t == 0) out[Bc*Kc + 2*Vc*Kc + Kc] = ws[WS_QZ];
    }
}

__global__ void k4_pi(const float* __restrict__ ws, float* __restrict__ out) {
    int k = threadIdx.x;
    if (k < Kc) {
        float ssn = ws[WS_SSNEW + k];
        float srs = ws[WS_GSR + k];
        float p = ssn / (ssn + srs + 1e-6f);
        out[Bc*Kc + 2*Vc*Kc + k] = (p > 0.1f) ? p : 0.7f;
    }
}

// ================= Fallback path (round-1 monolith) ==========================
__global__ __launch_bounds__(512) void fb_k2(
    const int* __restrict__ bow, const int* __restrict__ bidx,
    const float* __restrict__ seeds, const float* __restrict__ exp_m,
    const float* __restrict__ exp_n, const float* __restrict__ exp_s,
    const float* __restrict__ pi, float* __restrict__ ws,
    float* __restrict__ out)
{
    float* out_m = out;
    float* out_n = out + Bc*Kc;
    float* out_s = out + Bc*Kc + Vc*Kc;

    __shared__ float lds_m[Bc*Kc];
    __shared__ float lds_theta[Bc*Kc];
    __shared__ float lds_srsum[Kc];
    __shared__ float lds_qz;

    const int t = threadIdx.x;
    for (int i = t; i < Bc*Kc; i += 512) lds_m[i] = 0.f;
    if (t < Kc) lds_srsum[t] = 0.f;
    if (t == 0) lds_qz = 0.f;
    for (int i = t; i < Bc*Kc; i += 512) {
        int b = i / Kc;
        lds_theta[i] = exp_m[bidx[b]*Kc + (i - b*Kc)] + 0.1f;
    }
    __syncthreads();

    const int lane = t & 63;
    const int wid  = t >> 6;
    const int gw   = blockIdx.x * 8 + wid;
    const int nw   = gridDim.x * 8;
    const int k    = lane;
    const bool kval = (k < Kc);

    const float S_f      = (float)(((const int*)ws)[WS_SCNT]);
    const float mu_sum   = 0.1f * S_f;
    const float beta_sum = 0.1f * (float)Vc;
    float pi_k = 0.f, omp_k = 0.f, sden_inv = 0.f, rden_inv = 0.f;
    if (kval) {
        pi_k = pi[k];
        omp_k = 1.f - pi_k;
        sden_inv = 1.f / (mu_sum + ws[Kc + k]);
        rden_inv = 1.f / (beta_sum + ws[k]);
    }

    float acc_sr = 0.f, acc_qz = 0.f;

    for (int v = gw; v < Vc; v += nw) {
        float seeds_vk = 0.f, es = 0.f, en = 0.f;
        if (kval) {
            seeds_vk = seeds[v*Kc + k];
            es = exp_s[v*Kc + k];
            en = exp_n[v*Kc + k];
        }
        const float st = (0.1f + es) * sden_inv;
        const float rt = (0.1f + en) * rden_inv;
        const bool seed_word = (__ballot(seeds_vk != 0.f) != 0ULL);
        const float bow_lane = (float)bow[lane*Vc + v];

        float acc_n = 0.f, acc_s = 0.f;

        for (int b = 0; b < Bc; ++b) {
            const float bw = __shfl(bow_lane, b);
            if (bw == 0.f) continue;
            const float th = lds_theta[b*Kc + (kval ? k : 0)];
            float ss = seeds_vk * th * st * pi_k;
            float sr = seeds_vk * th * rt * omp_k;
            float rr = (1.f - seeds_vk) * th * rt;
            float ssum = ss + sr;
            float rsum = rr;
            for (int off = 32; off > 0; off >>= 1) {
                ssum += __shfl_xor(ssum, off);
                rsum += __shfl_xor(rsum, off);
            }
            const float inv_s = __builtin_amdgcn_rcpf(ssum + 1e-6f);
            const float inv_r = __builtin_amdgcn_rcpf(rsum + 1e-6f);
            const float ssn = ss * inv_s;
            const float srn = sr * inv_s;
            const float rrn = rr * inv_r;
            const float g = seed_word ? (pi_k*ssn + omp_k*(srn + rrn)) : rrn;
            acc_n  += (srn + rrn) * bw;
            acc_s  += ssn * bw;
            acc_sr += srn;
            acc_qz += g * __logf(g + 1e-6f);
            if (kval) atomicAdd(&lds_m[b*Kc + k], g * bw);
        }
        if (kval) {
            out_n[v*Kc + k] = acc_n;
            out_s[v*Kc + k] = acc_s;
        }
    }

    if (kval) atomicAdd(&lds_srsum[k], acc_sr);
    for (int off = 32; off > 0; off >>= 1) acc_qz += __shfl_xor(acc_qz, off);
    if (lane == 0) atomicAdd(&lds_qz, acc_qz);
    __syncthreads();

    for (int i = t; i < Bc*Kc; i += 512) {
        float vtm = lds_m[i];
        if (vtm != 0.f) atomicAdd(&out_m[i], vtm);
    }
    if (t < Kc) atomicAdd(&ws[WS_GSR + t], lds_srsum[t]);
    if (t == 0) atomicAdd(&ws[WS_QZ], lds_qz);
}

__global__ __launch_bounds__(256) void fb_k3(
    const float* __restrict__ exp_m, const float* __restrict__ exp_n,
    const float* __restrict__ exp_s, const int* __restrict__ bidx,
    const int* __restrict__ itern_p, float* __restrict__ out,
    float* __restrict__ ws)
{
    const int t = threadIdx.x, blk = blockIdx.x;
    int ii = itern_p[0];
    float itern = (ii >= 0 && ii < 1000000) ? (float)ii : __int_as_float(ii);
    const float rho = 1.f / powf(itern + 5.f, 0.9f);
    const float omr = 1.f - rho;
    const float bC  = (float)(((const int*)ws)[WS_BATCHC]);
    const float scale = 1e7f / bC;
    float* out_m = out;
    float* out_n = out + Bc*Kc;
    float* out_s = out + Bc*Kc + Vc*Kc;

    if (blk < Kc) {
        const int k = blk;
        float acc = 0.f;
        for (int v = t; v < Vc; v += 256) {
            int i = v*Kc + k;
            out_n[i] = omr*exp_n[i] + rho*scale*out_n[i];
            float snew = omr*exp_s[i] + rho*scale*out_s[i];
            out_s[i] = snew;
            acc += snew;
        }
        __shared__ float redf[256];
        redf[t] = acc; __syncthreads();
        for (int s = 128; s > 0; s >>= 1) { if (t < s) redf[t] += redf[t+s]; __syncthreads(); }
        if (t == 0) ws[WS_SSNEW + k] = redf[0];
    } else {
        for (int i = t; i < Bc*Kc; i += 256) {
            int b = i / Kc;
            out_m[i] = omr*exp_m[bidx[b]*Kc + (i - b*Kc)] + rho*out_m[i];
        }
        if (t == 0) out[Bc*Kc + 2*Vc*Kc + Kc] = ws[WS_QZ];
    }
}

// =============================================================================
extern "C" void kernel_launch(void* const* d_in, const int* in_sizes, int n_in,
                              void* d_out, int out_size, void* d_ws, size_t ws_size,
                              hipStream_t stream)
{
    const int*   bow    = (const int*)d_in[0];
    const int*   bidx   = (const int*)d_in[1];
    const float* seeds  = (const float*)d_in[2];
    const float* exp_m  = (const float*)d_in[3];
    const float* exp_n  = (const float*)d_in[4];
    const float* exp_s  = (const float*)d_in[5];
    const float* pi     = (const float*)d_in[6];
    const int*   iter_n = (const int*)d_in[7];
    float* out = (float*)d_out;
    float* ws  = (float*)d_ws;

    const size_t needed = (size_t)WS_END * sizeof(float);
    if (ws_size >= needed) {
        hipMemsetAsync(d_ws, 0, 16384, stream);   // scalars + pm accumulators
        k1_pre<<<Kc + 32 + 8, 256, 0, stream>>>(bow, seeds, exp_n, exp_s, ws, ws + WS_SW);
        kA0<<<(Bc*Vc + 255)/256, 256, 0, stream>>>(bow, (int*)ws + WS_BT);
        kA1<<<(Vc*Kc + 255)/256, 256, 0, stream>>>(seeds, exp_n, exp_s, pi, ws);
        kBD<<<384, 512, 0, stream>>>(bidx, exp_m, pi, ws);
        kC<<<500, 512, 0, stream>>>(bidx, exp_m, ws, out);
        k3_fin2<<<Kc + 1, 256, 0, stream>>>(exp_m, exp_n, exp_s, bidx, iter_n, out, ws);
        k4_pi<<<1, 64, 0, stream>>>(ws, out);
    } else {
        // fallback: round-1 monolith (small ws footprint)
        hipMemsetAsync(d_ws, 0, 1024, stream);
        hipMemsetAsync(d_out, 0, Bc*Kc*sizeof(float), stream);
        k1_pre<<<Kc + 32 + 8, 256, 0, stream>>>(bow, seeds, exp_n, exp_s, ws, nullptr);
        fb_k2<<<256, 512, 0, stream>>>(bow, bidx, seeds, exp_m, exp_n, exp_s, pi, ws, out);
        fb_k3<<<Kc + 1, 256, 0, stream>>>(exp_m, exp_n, exp_s, bidx, iter_n, out, ws);
        k4_pi<<<1, 64, 0, stream>>>(ws, out);
    }
}

// Round 3
// 189.709 us; speedup vs baseline: 1.3217x; 1.3217x over previous
//
#include <hip/hip_runtime.h>
#include <math.h>

constexpr int Bc = 64;      // batch
constexpr int Vc = 8000;    // vocab
constexpr int Kc = 50;      // topics

// ws float-offsets
#define WS_NSUM   0        // 50  exp_n colsum (atomic)
#define WS_SSUM   50       // 50  exp_s colsum (atomic)
#define WS_QZ     150      // exp_q_z (atomic f32)
#define WS_BATCHC 151      // batch_C (atomic int)
#define WS_SCNT   152      // seed-word count (atomic int)
#define WS_PM     256      // 64*50 temp_m pre-theta (atomic f32)
#define WS_GSRSH  3456     // 64*50 gamma_sr_sum shards
#define WS_SSNSH  6656     // 32*50 exp_s_sum_new shards
#define WS_SW     8256     // 8000 seed-word flags
#define WS_CD     16384                  // float2 [k][v]: (C=sc+n1, D=n2)
#define WS_GEGF   (WS_CD + 2*Vc*Kc)      // float2 [k][v]: (GE, GF)
#define WS_IS     (WS_GEGF + 2*Vc*Kc)    // [b][v] mask/(S+eps)
#define WS_IR     (WS_IS + Bc*Vc)        // [b][v] mask/(R+eps)
#define WS_END    (WS_IR + Bc*Vc)        // 2640384 floats = 10.56 MB

// ---------------- k1: colsums (flat coalesced), batch_C, seed flags ----------
__global__ __launch_bounds__(256) void k1_pre(const int* __restrict__ bow,
    const float* __restrict__ seeds, const float* __restrict__ exp_n,
    const float* __restrict__ exp_s, float* __restrict__ ws)
{
    const int t = threadIdx.x, blk = blockIdx.x;
    if (blk < 32) {
        __shared__ float csn[Kc], css[Kc];
        for (int i = t; i < Kc; i += 256) { csn[i] = 0.f; css[i] = 0.f; }
        __syncthreads();
        for (int i = blk*256 + t; i < Vc*Kc; i += 32*256) {
            int k = i % Kc;
            atomicAdd(&csn[k], exp_n[i]);
            atomicAdd(&css[k], exp_s[i]);
        }
        __syncthreads();
        if (t < Kc) {
            atomicAdd(&ws[WS_NSUM + t], csn[t]);
            atomicAdd(&ws[WS_SSUM + t], css[t]);
        }
    } else if (blk < 40) {
        __shared__ int redi[256];
        int acc = 0;
        for (int i = (blk-32)*256 + t; i < Bc*Vc; i += 8*256) acc += bow[i];
        redi[t] = acc; __syncthreads();
        for (int s = 128; s > 0; s >>= 1) { if (t < s) redi[t] += redi[t+s]; __syncthreads(); }
        if (t == 0) atomicAdd((int*)ws + WS_BATCHC, redi[0]);
    } else {
        __shared__ int redi[256];
        int cnt = 0;
        for (int v = (blk-40)*256 + t; v < Vc; v += 8*256) {
            const float* row = seeds + v*Kc;
            int any = 0;
            for (int k = 0; k < Kc; ++k) any |= (row[k] != 0.f);
            cnt += any;
            ws[WS_SW + v] = any ? 1.f : 0.f;
        }
        redi[t] = cnt; __syncthreads();
        for (int s = 128; s > 0; s >>= 1) { if (t < s) redi[t] += redi[t+s]; __syncthreads(); }
        if (t == 0) atomicAdd((int*)ws + WS_SCNT, redi[0]);
    }
}

// ---------------- kA1: tiled transpose + coefficient build -------------------
// Writes CD[k][v] = (sc+n1, n2) and GEGF[k][v] = (GE, GF) as float2, coalesced.
__global__ __launch_bounds__(256) void kA1(const float* __restrict__ seeds,
    const float* __restrict__ exp_n, const float* __restrict__ exp_s,
    const float* __restrict__ pi, float* __restrict__ ws)
{
    __shared__ float tsv[64*51], ten[64*51], tes[64*51];
    const int t = threadIdx.x;
    const int v0 = blockIdx.x * 64;
    for (int i = t; i < 64*Kc; i += 256) {
        int vl = i / Kc, k = i - vl*Kc;
        int gi = (v0 + vl)*Kc + k;           // coalesced reads
        tsv[vl*51 + k] = seeds[gi];
        ten[vl*51 + k] = exp_n[gi];
        tes[vl*51 + k] = exp_s[gi];
    }
    __syncthreads();
    const float Sf = (float)(((const int*)ws)[WS_SCNT]);
    const float musum = 0.1f*Sf, betasum = 0.1f*(float)Vc;
    float2* CD   = (float2*)(ws + WS_CD);
    float2* GEGF = (float2*)(ws + WS_GEGF);
    for (int i = t; i < 64*Kc; i += 256) {
        int k = i >> 6, vl = i & 63;         // k uniform per wave -> scalar denom loads
        float sv = tsv[vl*51 + k], en = ten[vl*51 + k], es = tes[vl*51 + k];
        float pk = pi[k];
        float st = (0.1f + es) / (musum   + ws[WS_SSUM + k]);
        float rt = (0.1f + en) / (betasum + ws[WS_NSUM + k]);
        float sc = sv*st*pk, n1 = sv*rt*(1.f - pk), n2 = (1.f - sv)*rt;
        float swv = ws[WS_SW + v0 + vl];
        float ge = fmaf(pk, sc, (1.f - pk)*n1);
        float gf = (swv != 0.f) ? (1.f - pk)*n2 : n2;
        CD  [(size_t)k*Vc + v0 + vl] = make_float2(sc + n1, n2);
        GEGF[(size_t)k*Vc + v0 + vl] = make_float2(ge, gf);
    }
}

// ---------------- kMAIN: per-(b,v) S,R -> is/ir; pm; qz ----------------------
// grid (16 v-panels, 64 b). Streams CD/GEGF coalesced; theta uniform (SGPR).
__global__ __launch_bounds__(256, 2) void kMAIN(const int* __restrict__ bow,
    const int* __restrict__ bidx, const float* __restrict__ exp_m,
    float* __restrict__ ws)
{
    const int t = threadIdx.x;
    const int b = blockIdx.y;
    const int doc = bidx[b];                 // block-uniform
    float th[Kc];
#pragma unroll
    for (int k = 0; k < Kc; ++k) th[k] = exp_m[doc*Kc + k] + 0.1f;   // uniform loads

    const float2* CD   = (const float2*)(ws + WS_CD);
    const float2* GEGF = (const float2*)(ws + WS_GEGF);
    float* ISg = ws + WS_IS;
    float* IRg = ws + WS_IR;

    float pm[Kc];
#pragma unroll
    for (int k = 0; k < Kc; ++k) pm[k] = 0.f;
    float qz = 0.f;

    const int v0 = blockIdx.x * 512;
#pragma unroll
    for (int half = 0; half < 2; ++half) {
        const int v = v0 + half*256 + t;
        if (v < Vc) {
            const float bw = (float)bow[b*Vc + v];     // coalesced
            float S = 0.f, S2 = 0.f, R = 0.f, R2 = 0.f;
#pragma unroll
            for (int k = 0; k < Kc; k += 2) {
                float2 cd0 = CD[(size_t)k*Vc + v];
                float2 cd1 = CD[(size_t)(k+1)*Vc + v];
                S  = fmaf(th[k],   cd0.x, S);  R  = fmaf(th[k],   cd0.y, R);
                S2 = fmaf(th[k+1], cd1.x, S2); R2 = fmaf(th[k+1], cd1.y, R2);
            }
            S += S2; R += R2;
            const bool msk = bw > 0.f;
            const float is = msk ? 1.f/(S + 1e-6f) : 0.f;
            const float ir = msk ? 1.f/(R + 1e-6f) : 0.f;
            ISg[b*Vc + v] = is;
            IRg[b*Vc + v] = ir;
#pragma unroll
            for (int k = 0; k < Kc; ++k) {
                float2 gg = GEGF[(size_t)k*Vc + v];
                float t1 = fmaf(gg.x, is, gg.y*ir);
                float g  = th[k]*t1;
                qz = fmaf(g, __logf(g + 1e-6f), qz);
                pm[k] = fmaf(bw, t1, pm[k]);
            }
        }
    }

    // wave-level butterfly reduce (b is wave-uniform), then one lane flushes
#pragma unroll
    for (int k = 0; k < Kc; ++k) {
        float x = pm[k];
        for (int off = 32; off; off >>= 1) x += __shfl_xor(x, off);
        pm[k] = x;
    }
    for (int off = 32; off; off >>= 1) qz += __shfl_xor(qz, off);
    if ((t & 63) == 0) {
#pragma unroll
        for (int k = 0; k < Kc; ++k) atomicAdd(&ws[WS_PM + b*Kc + k], pm[k]);
        atomicAdd(&ws[WS_QZ], qz);
    }
}

// ---------------- kC: temp_n, temp_s, gamma_sr_sum ---------------------------
// block = 4 v's (one per wave), lanes = k. All inner operands LDS broadcasts.
__global__ __launch_bounds__(256) void kC(const int* __restrict__ bow,
    const int* __restrict__ bidx, const float* __restrict__ exp_m,
    const float* __restrict__ seeds, const float* __restrict__ exp_n,
    const float* __restrict__ exp_s, const float* __restrict__ pi,
    float* __restrict__ ws, float* __restrict__ out)
{
    __shared__ float th_l[Bc*51];
    __shared__ float4 uwis[Bc*4];
    const int t = threadIdx.x;
    const int v0 = blockIdx.x * 4;
    for (int i = t; i < Bc*Kc; i += 256) {
        int bb = i / Kc, k = i - bb*Kc;
        th_l[bb*51 + k] = exp_m[bidx[bb]*Kc + k] + 0.1f;
    }
    {
        int bb = t >> 2, vl = t & 3;
        int gi = bb*Vc + v0 + vl;
        float is = ws[WS_IS + gi], ir = ws[WS_IR + gi];
        float bw = (float)bow[gi];
        uwis[t] = make_float4(bw*is, bw*ir, is, 0.f);
    }
    __syncthreads();
    const int lane = t & 63, w = t >> 6;
    const int v = v0 + w;
    float PT = 0.f, QT = 0.f, P2 = 0.f;
#pragma unroll 8
    for (int bb = 0; bb < Bc; ++bb) {
        float4 u = uwis[bb*4 + w];               // uniform -> one b128 broadcast
        float thv = th_l[bb*51 + lane];
        PT = fmaf(u.x, thv, PT);
        QT = fmaf(u.y, thv, QT);
        P2 = fmaf(u.z, thv, P2);
    }
    if (lane < Kc) {
        const float Sf = (float)(((const int*)ws)[WS_SCNT]);
        int gi = v*Kc + lane;                    // coalesced input reads
        float sv = seeds[gi], en = exp_n[gi], es = exp_s[gi];
        float pk = pi[lane];
        float st = (0.1f + es) / (0.1f*Sf + ws[WS_SSUM + lane]);
        float rt = (0.1f + en) / (0.1f*(float)Vc + ws[WS_NSUM + lane]);
        float sc = sv*st*pk, n1 = sv*rt*(1.f - pk), n2 = (1.f - sv)*rt;
        out[Bc*Kc + gi]         = fmaf(n1, PT, n2*QT);   // temp_exp_n staging
        out[Bc*Kc + Vc*Kc + gi] = sc*PT;                 // temp_exp_s staging
        atomicAdd(&ws[WS_GSRSH + (blockIdx.x & 63)*Kc + lane], n1*P2);
    }
}

// ---------------- k3: finalize n/s (flat, coalesced) + m + qz ----------------
__global__ __launch_bounds__(256) void k3_fin(
    const float* __restrict__ exp_m, const float* __restrict__ exp_n,
    const float* __restrict__ exp_s, const int* __restrict__ bidx,
    const int* __restrict__ itern_p, float* __restrict__ out,
    float* __restrict__ ws)
{
    const int t = threadIdx.x, blk = blockIdx.x;
    int ii = itern_p[0];
    float itern = (ii >= 0 && ii < 1000000) ? (float)ii : __int_as_float(ii);
    const float rho = 1.f / powf(itern + 5.f, 0.9f);
    const float omr = 1.f - rho;
    const float bC  = (float)(((const int*)ws)[WS_BATCHC]);
    const float rs  = rho * (1e7f / bC);
    float* out_m = out;
    float* out_n = out + Bc*Kc;
    float* out_s = out + Bc*Kc + Vc*Kc;
    const int NB = (Vc*Kc + 255) / 256;     // 1563

    if (blk < NB) {
        __shared__ float ssl[Kc];
        for (int i = t; i < Kc; i += 256) ssl[i] = 0.f;
        __syncthreads();
        int i = blk*256 + t;
        if (i < Vc*Kc) {
            int k = i % Kc;
            out_n[i] = fmaf(omr, exp_n[i], rs*out_n[i]);
            float snew = fmaf(omr, exp_s[i], rs*out_s[i]);
            out_s[i] = snew;
            atomicAdd(&ssl[k], snew);
        }
        __syncthreads();
        if (t < Kc) atomicAdd(&ws[WS_SSNSH + (blk & 31)*Kc + t], ssl[t]);
    } else {
        for (int i = t; i < Bc*Kc; i += 256) {
            int bb = i / Kc, k = i - bb*Kc;
            float th = exp_m[bidx[bb]*Kc + k] + 0.1f;
            out_m[i] = fmaf(omr, th - 0.1f, rho*th*ws[WS_PM + i]);
        }
        if (t == 0) out[Bc*Kc + 2*Vc*Kc + Kc] = ws[WS_QZ];
    }
}

__global__ void k4_pi(const float* __restrict__ ws, float* __restrict__ out) {
    int k = threadIdx.x;
    if (k < Kc) {
        float ssn = 0.f, srs = 0.f;
        for (int s = 0; s < 32; ++s) ssn += ws[WS_SSNSH + s*Kc + k];
        for (int s = 0; s < 64; ++s) srs += ws[WS_GSRSH + s*Kc + k];
        float p = ssn / (ssn + srs + 1e-6f);
        out[Bc*Kc + 2*Vc*Kc + k] = (p > 0.1f) ? p : 0.7f;
    }
}

// ================= Fallback path (round-1 monolith, small ws) ================
__global__ __launch_bounds__(256) void fb_k1(const int* __restrict__ bow,
    const float* __restrict__ seeds, const float* __restrict__ exp_n,
    const float* __restrict__ exp_s, float* __restrict__ ws)
{
    __shared__ float redf[256];
    __shared__ int   redi[256];
    const int t = threadIdx.x, blk = blockIdx.x;
    if (blk < Kc) {
        float sn = 0.f, ss = 0.f;
        for (int v = t; v < Vc; v += 256) {
            sn += exp_n[v*Kc + blk];
            ss += exp_s[v*Kc + blk];
        }
        redf[t] = sn; __syncthreads();
        for (int s = 128; s > 0; s >>= 1) { if (t < s) redf[t] += redf[t+s]; __syncthreads(); }
        if (t == 0) ws[WS_NSUM + blk] = redf[0];
        __syncthreads();
        redf[t] = ss; __syncthreads();
        for (int s = 128; s > 0; s >>= 1) { if (t < s) redf[t] += redf[t+s]; __syncthreads(); }
        if (t == 0) ws[WS_SSUM + blk] = redf[0];
    } else if (blk < Kc + 32) {
        int acc = 0;
        for (int i = (blk - Kc)*256 + t; i < Bc*Vc; i += 32*256) acc += bow[i];
        redi[t] = acc; __syncthreads();
        for (int s = 128; s > 0; s >>= 1) { if (t < s) redi[t] += redi[t+s]; __syncthreads(); }
        if (t == 0) atomicAdd((int*)ws + WS_BATCHC, redi[0]);
    } else {
        int cnt = 0;
        for (int v = (blk - Kc - 32)*256 + t; v < Vc; v += 8*256) {
            const float* row = seeds + v*Kc;
            int any = 0;
            for (int k = 0; k < Kc; ++k) any |= (row[k] != 0.f);
            cnt += any;
        }
        redi[t] = cnt; __syncthreads();
        for (int s = 128; s > 0; s >>= 1) { if (t < s) redi[t] += redi[t+s]; __syncthreads(); }
        if (t == 0) atomicAdd((int*)ws + WS_SCNT, redi[0]);
    }
}

__global__ __launch_bounds__(512) void fb_k2(
    const int* __restrict__ bow, const int* __restrict__ bidx,
    const float* __restrict__ seeds, const float* __restrict__ exp_m,
    const float* __restrict__ exp_n, const float* __restrict__ exp_s,
    const float* __restrict__ pi, float* __restrict__ ws,
    float* __restrict__ out)
{
    float* out_m = out;
    float* out_n = out + Bc*Kc;
    float* out_s = out + Bc*Kc + Vc*Kc;
    __shared__ float lds_m[Bc*Kc];
    __shared__ float lds_theta[Bc*Kc];
    __shared__ float lds_srsum[Kc];
    __shared__ float lds_qz;
    const int t = threadIdx.x;
    for (int i = t; i < Bc*Kc; i += 512) lds_m[i] = 0.f;
    if (t < Kc) lds_srsum[t] = 0.f;
    if (t == 0) lds_qz = 0.f;
    for (int i = t; i < Bc*Kc; i += 512) {
        int b = i / Kc;
        lds_theta[i] = exp_m[bidx[b]*Kc + (i - b*Kc)] + 0.1f;
    }
    __syncthreads();
    const int lane = t & 63, wid = t >> 6;
    const int gw = blockIdx.x*8 + wid, nw = gridDim.x*8;
    const int k = lane;
    const bool kval = (k < Kc);
    const float S_f = (float)(((const int*)ws)[WS_SCNT]);
    float pi_k = 0.f, omp_k = 0.f, sden_inv = 0.f, rden_inv = 0.f;
    if (kval) {
        pi_k = pi[k]; omp_k = 1.f - pi_k;
        sden_inv = 1.f / (0.1f*S_f + ws[WS_SSUM + k]);
        rden_inv = 1.f / (0.1f*(float)Vc + ws[WS_NSUM + k]);
    }
    float acc_sr = 0.f, acc_qz = 0.f;
    for (int v = gw; v < Vc; v += nw) {
        float seeds_vk = 0.f, es = 0.f, en = 0.f;
        if (kval) { seeds_vk = seeds[v*Kc+k]; es = exp_s[v*Kc+k]; en = exp_n[v*Kc+k]; }
        const float st = (0.1f + es)*sden_inv;
        const float rt = (0.1f + en)*rden_inv;
        const bool seed_word = (__ballot(seeds_vk != 0.f) != 0ULL);
        const float bow_lane = (float)bow[lane*Vc + v];
        float acc_n = 0.f, acc_s = 0.f;
        for (int b = 0; b < Bc; ++b) {
            const float bw = __shfl(bow_lane, b);
            if (bw == 0.f) continue;
            const float th = lds_theta[b*Kc + (kval ? k : 0)];
            float ss = seeds_vk*th*st*pi_k;
            float sr = seeds_vk*th*rt*omp_k;
            float rr = (1.f - seeds_vk)*th*rt;
            float ssum = ss + sr, rsum = rr;
            for (int off = 32; off > 0; off >>= 1) {
                ssum += __shfl_xor(ssum, off);
                rsum += __shfl_xor(rsum, off);
            }
            const float inv_s = __builtin_amdgcn_rcpf(ssum + 1e-6f);
            const float inv_r = __builtin_amdgcn_rcpf(rsum + 1e-6f);
            const float ssn = ss*inv_s, srn = sr*inv_s, rrn = rr*inv_r;
            const float g = seed_word ? (pi_k*ssn + omp_k*(srn + rrn)) : rrn;
            acc_n += (srn + rrn)*bw;
            acc_s += ssn*bw;
            acc_sr += srn;
            acc_qz += g*__logf(g + 1e-6f);
            if (kval) atomicAdd(&lds_m[b*Kc + k], g*bw);
        }
        if (kval) { out_n[v*Kc + k] = acc_n; out_s[v*Kc + k] = acc_s; }
    }
    if (kval) atomicAdd(&lds_srsum[k], acc_sr);
    for (int off = 32; off > 0; off >>= 1) acc_qz += __shfl_xor(acc_qz, off);
    if (lane == 0) atomicAdd(&lds_qz, acc_qz);
    __syncthreads();
    for (int i = t; i < Bc*Kc; i += 512) {
        float vtm = lds_m[i];
        if (vtm != 0.f) atomicAdd(&out_m[i], vtm);
    }
    if (t < Kc) atomicAdd(&ws[WS_GSRSH + t], lds_srsum[t]);
    if (t == 0) atomicAdd(&ws[WS_QZ], lds_qz);
}

__global__ __launch_bounds__(256) void fb_k3(
    const float* __restrict__ exp_m, const float* __restrict__ exp_n,
    const float* __restrict__ exp_s, const int* __restrict__ bidx,
    const int* __restrict__ itern_p, float* __restrict__ out,
    float* __restrict__ ws)
{
    const int t = threadIdx.x, blk = blockIdx.x;
    int ii = itern_p[0];
    float itern = (ii >= 0 && ii < 1000000) ? (float)ii : __int_as_float(ii);
    const float rho = 1.f / powf(itern + 5.f, 0.9f);
    const float omr = 1.f - rho;
    const float bC = (float)(((const int*)ws)[WS_BATCHC]);
    const float scale = 1e7f / bC;
    float* out_m = out;
    float* out_n = out + Bc*Kc;
    float* out_s = out + Bc*Kc + Vc*Kc;
    if (blk < Kc) {
        const int k = blk;
        float acc = 0.f;
        for (int v = t; v < Vc; v += 256) {
            int i = v*Kc + k;
            out_n[i] = omr*exp_n[i] + rho*scale*out_n[i];
            float snew = omr*exp_s[i] + rho*scale*out_s[i];
            out_s[i] = snew;
            acc += snew;
        }
        __shared__ float redf[256];
        redf[t] = acc; __syncthreads();
        for (int s = 128; s > 0; s >>= 1) { if (t < s) redf[t] += redf[t+s]; __syncthreads(); }
        if (t == 0) ws[WS_SSNSH + k] = redf[0];
    } else {
        for (int i = t; i < Bc*Kc; i += 256) {
            int b = i / Kc;
            out_m[i] = omr*exp_m[bidx[b]*Kc + (i - b*Kc)] + rho*out_m[i];
        }
        if (t == 0) out[Bc*Kc + 2*Vc*Kc + Kc] = ws[WS_QZ];
    }
}

__global__ void fb_k4(const float* __restrict__ ws, float* __restrict__ out) {
    int k = threadIdx.x;
    if (k < Kc) {
        float ssn = ws[WS_SSNSH + k];
        float srs = ws[WS_GSRSH + k];
        float p = ssn / (ssn + srs + 1e-6f);
        out[Bc*Kc + 2*Vc*Kc + k] = (p > 0.1f) ? p : 0.7f;
    }
}

// =============================================================================
extern "C" void kernel_launch(void* const* d_in, const int* in_sizes, int n_in,
                              void* d_out, int out_size, void* d_ws, size_t ws_size,
                              hipStream_t stream)
{
    const int*   bow    = (const int*)d_in[0];
    const int*   bidx   = (const int*)d_in[1];
    const float* seeds  = (const float*)d_in[2];
    const float* exp_m  = (const float*)d_in[3];
    const float* exp_n  = (const float*)d_in[4];
    const float* exp_s  = (const float*)d_in[5];
    const float* pi     = (const float*)d_in[6];
    const int*   iter_n = (const int*)d_in[7];
    float* out = (float*)d_out;
    float* ws  = (float*)d_ws;

    if (ws_size >= (size_t)WS_END * sizeof(float)) {
        hipMemsetAsync(d_ws, 0, 33280, stream);   // scalars + pm + shards
        k1_pre<<<48, 256, 0, stream>>>(bow, seeds, exp_n, exp_s, ws);
        kA1<<<Vc/64, 256, 0, stream>>>(seeds, exp_n, exp_s, pi, ws);
        kMAIN<<<dim3(16, 64), 256, 0, stream>>>(bow, bidx, exp_m, ws);
        kC<<<Vc/4, 256, 0, stream>>>(bow, bidx, exp_m, seeds, exp_n, exp_s, pi, ws, out);
        k3_fin<<<(Vc*Kc + 255)/256 + 1, 256, 0, stream>>>(exp_m, exp_n, exp_s, bidx, iter_n, out, ws);
        k4_pi<<<1, 64, 0, stream>>>(ws, out);
    } else {
        hipMemsetAsync(d_ws, 0, 33280 < ws_size ? 33280 : ws_size, stream);
        hipMemsetAsync(d_out, 0, Bc*Kc*sizeof(float), stream);
        fb_k1<<<Kc + 32 + 8, 256, 0, stream>>>(bow, seeds, exp_n, exp_s, ws);
        fb_k2<<<256, 512, 0, stream>>>(bow, bidx, seeds, exp_m, exp_n, exp_s, pi, ws, out);
        fb_k3<<<Kc + 1, 256, 0, stream>>>(exp_m, exp_n, exp_s, bidx, iter_n, out, ws);
        fb_k4<<<1, 64, 0, stream>>>(ws, out);
    }
}

// Round 4
// 150.905 us; speedup vs baseline: 1.6616x; 1.2571x over previous
//
#include <hip/hip_runtime.h>
#include <math.h>

constexpr int Bc = 64;      // batch
constexpr int Vc = 8000;    // vocab
constexpr int Kc = 50;      // topics

// ws float-offsets (low region zeroed by memset)
#define WS_NSUM   0        // 50  exp_n colsum (atomic)
#define WS_SSUM   50       // 50  exp_s colsum (atomic)
#define WS_GSR    100      // unused (fallback uses)
#define WS_QZ     150      // fallback qz
#define WS_BATCHC 151      // batch_C (atomic int)
#define WS_SCNT   152      // seed-word count (atomic int)
#define WS_QZSH   220      // 32 qz shards
#define WS_PM     256      // 64*50 temp_m pre-theta (atomic f32)
#define WS_GSRSH  3456     // 64*50 gamma_sr_sum shards
#define WS_SSNSH  6656     // 32*50 exp_s_sum_new shards
#define WS_SW     8256     // 8000 seed-word flags
#define WS_CD2    16384                    // float4 [k2][v]: (C0,D0,C1,D1)
#define WS_GG2    (WS_CD2 + Vc*Kc*2)       // float4 [k2][v]: (ge0,gf0,ge1,gf1)
#define WS_ISIR   (WS_GG2 + Vc*Kc*2)       // float2 [b][v]: (is, ir)
#define WS_END    (WS_ISIR + 2*Bc*Vc)      // 2640384 floats = 10.56 MB

// ---------------- k1: colsums, batch_C, seed flags ---------------------------
__global__ __launch_bounds__(256) void k1_pre(const int* __restrict__ bow,
    const float* __restrict__ seeds, const float* __restrict__ exp_n,
    const float* __restrict__ exp_s, float* __restrict__ ws)
{
    const int t = threadIdx.x, blk = blockIdx.x;
    if (blk < 32) {
        __shared__ float csn[Kc], css[Kc];
        for (int i = t; i < Kc; i += 256) { csn[i] = 0.f; css[i] = 0.f; }
        __syncthreads();
        for (int i = blk*256 + t; i < Vc*Kc; i += 32*256) {
            int k = i % Kc;
            atomicAdd(&csn[k], exp_n[i]);
            atomicAdd(&css[k], exp_s[i]);
        }
        __syncthreads();
        if (t < Kc) {
            atomicAdd(&ws[WS_NSUM + t], csn[t]);
            atomicAdd(&ws[WS_SSUM + t], css[t]);
        }
    } else if (blk < 40) {
        __shared__ int redi[256];
        int acc = 0;
        for (int i = (blk-32)*256 + t; i < Bc*Vc; i += 8*256) acc += bow[i];
        redi[t] = acc; __syncthreads();
        for (int s = 128; s > 0; s >>= 1) { if (t < s) redi[t] += redi[t+s]; __syncthreads(); }
        if (t == 0) atomicAdd((int*)ws + WS_BATCHC, redi[0]);
    } else {
        __shared__ int redi[256];
        int cnt = 0;
        for (int v = (blk-40)*256 + t; v < Vc; v += 8*256) {
            const float* row = seeds + v*Kc;
            int any = 0;
            for (int k = 0; k < Kc; ++k) any |= (row[k] != 0.f);
            cnt += any;
            ws[WS_SW + v] = any ? 1.f : 0.f;
        }
        redi[t] = cnt; __syncthreads();
        for (int s = 128; s > 0; s >>= 1) { if (t < s) redi[t] += redi[t+s]; __syncthreads(); }
        if (t == 0) atomicAdd((int*)ws + WS_SCNT, redi[0]);
    }
}

// ---------------- kA1: build packed float4 coefficient arrays ----------------
__global__ __launch_bounds__(256) void kA1(const float* __restrict__ seeds,
    const float* __restrict__ exp_n, const float* __restrict__ exp_s,
    const float* __restrict__ pi, float* __restrict__ ws)
{
    __shared__ float tsv[64*51], ten[64*51], tes[64*51];
    const int t = threadIdx.x;
    const int v0 = blockIdx.x * 64;
    for (int i = t; i < 64*Kc; i += 256) {
        int vl = i / Kc, k = i - vl*Kc;
        int gi = (v0 + vl)*Kc + k;           // coalesced reads
        tsv[vl*51 + k] = seeds[gi];
        ten[vl*51 + k] = exp_n[gi];
        tes[vl*51 + k] = exp_s[gi];
    }
    __syncthreads();
    const float Sf = (float)(((const int*)ws)[WS_SCNT]);
    const float musum = 0.1f*Sf, betasum = 0.1f*(float)Vc;
    float4* CD2 = (float4*)(ws + WS_CD2);
    float4* GG2 = (float4*)(ws + WS_GG2);
    for (int i = t; i < 64*(Kc/2); i += 256) {
        int k2 = i >> 6, vl = i & 63;        // k2 wave-uniform, vl consecutive
        float swv = ws[WS_SW + v0 + vl];
        float C[2], D[2], GE[2], GF[2];
#pragma unroll
        for (int h = 0; h < 2; ++h) {
            int k = 2*k2 + h;
            float sv = tsv[vl*51 + k], en = ten[vl*51 + k], es = tes[vl*51 + k];
            float pk = pi[k];
            float st = (0.1f + es) / (musum   + ws[WS_SSUM + k]);
            float rt = (0.1f + en) / (betasum + ws[WS_NSUM + k]);
            float sc = sv*st*pk, n1 = sv*rt*(1.f - pk), n2 = (1.f - sv)*rt;
            C[h] = sc + n1;  D[h] = n2;
            GE[h] = fmaf(pk, sc, (1.f - pk)*n1);
            GF[h] = (swv != 0.f) ? (1.f - pk)*n2 : n2;
        }
        CD2[(size_t)k2*Vc + v0 + vl] = make_float4(C[0], D[0], C[1], D[1]);
        GG2[(size_t)k2*Vc + v0 + vl] = make_float4(GE[0], GF[0], GE[1], GF[1]);
    }
}

// ---------------- kMAIN: per-(b,v) S,R -> is/ir; pm; qz ----------------------
// XCD-pinned: id&7 = XCD owns v-panels {2x,2x+1} (contiguous 1000 v's -> L2-resident
// CD2/GG2 slice of 800KB). One b per block; theta block-uniform (scalar loads).
__global__ __launch_bounds__(256, 2) void kMAIN(const int* __restrict__ bow,
    const int* __restrict__ bidx, const float* __restrict__ exp_m,
    float* __restrict__ ws)
{
    __shared__ float pm_l[Kc];
    __shared__ float qz_l;
    const int t = threadIdx.x;
    const int id = blockIdx.x;
    const int xcd = id & 7;
    const int j   = id >> 3;                 // 0..127
    const int vp  = xcd*2 + (j >> 6);        // 0..15, pinned to XCD
    const int b   = j & 63;

    if (t < Kc) pm_l[t] = 0.f;
    if (t == 0) qz_l = 0.f;
    __syncthreads();

    const int doc = bidx[b];                 // block-uniform
    float th[Kc];
#pragma unroll
    for (int k = 0; k < Kc; ++k) th[k] = exp_m[doc*Kc + k] + 0.1f;

    const float4* CD2 = (const float4*)(ws + WS_CD2);
    const float4* GG2 = (const float4*)(ws + WS_GG2);
    float2* isir = (float2*)(ws + WS_ISIR);

    float pm[Kc];
#pragma unroll
    for (int k = 0; k < Kc; ++k) pm[k] = 0.f;
    float qz = 0.f;

    for (int vv = t; vv < 500; vv += 256) {
        const int v = vp*500 + vv;
        const float bw = (float)bow[b*Vc + v];       // coalesced
        float S = 0.f, S2 = 0.f, R = 0.f, R2 = 0.f;
#pragma unroll
        for (int k2 = 0; k2 < Kc/2; ++k2) {
            float4 cd = CD2[(size_t)k2*Vc + v];      // (C0,D0,C1,D1)
            S  = fmaf(th[2*k2],   cd.x, S);  R  = fmaf(th[2*k2],   cd.y, R);
            S2 = fmaf(th[2*k2+1], cd.z, S2); R2 = fmaf(th[2*k2+1], cd.w, R2);
        }
        S += S2; R += R2;
        const bool msk = bw > 0.f;
        const float is = msk ? 1.f/(S + 1e-6f) : 0.f;
        const float ir = msk ? 1.f/(R + 1e-6f) : 0.f;
        isir[b*Vc + v] = make_float2(is, ir);
#pragma unroll
        for (int k2 = 0; k2 < Kc/2; ++k2) {
            float4 gg = GG2[(size_t)k2*Vc + v];      // (ge0,gf0,ge1,gf1)
            float t1a = fmaf(gg.x, is, gg.y*ir);
            float t1b = fmaf(gg.z, is, gg.w*ir);
            float ga = th[2*k2]*t1a;
            float gb = th[2*k2+1]*t1b;
            qz = fmaf(ga, __logf(ga + 1e-6f), qz);
            qz = fmaf(gb, __logf(gb + 1e-6f), qz);
            pm[2*k2]   = fmaf(bw, t1a, pm[2*k2]);
            pm[2*k2+1] = fmaf(bw, t1b, pm[2*k2+1]);
        }
    }

    // wave reduce, then block-level LDS reduce, then ONE flush per block
#pragma unroll
    for (int k = 0; k < Kc; ++k) {
        float x = pm[k];
        for (int off = 32; off; off >>= 1) x += __shfl_xor(x, off);
        pm[k] = x;
    }
    for (int off = 32; off; off >>= 1) qz += __shfl_xor(qz, off);
    if ((t & 63) == 0) {
#pragma unroll
        for (int k = 0; k < Kc; ++k) atomicAdd(&pm_l[k], pm[k]);
        atomicAdd(&qz_l, qz);
    }
    __syncthreads();
    if (t < Kc) atomicAdd(&ws[WS_PM + b*Kc + t], pm_l[t]);
    if (t == 64) atomicAdd(&ws[WS_QZSH + (id & 31)], qz_l);
}

// ---------------- kC: temp_n, temp_s, gamma_sr_sum ---------------------------
// 16 v per block (504 blocks, XCD-pinned to match kMAIN's isir locality).
__global__ __launch_bounds__(256) void kC(const int* __restrict__ bow,
    const int* __restrict__ bidx, const float* __restrict__ exp_m,
    const float* __restrict__ seeds, const float* __restrict__ exp_n,
    const float* __restrict__ exp_s, const float* __restrict__ pi,
    float* __restrict__ ws, float* __restrict__ out)
{
    const int id = blockIdx.x;
    const int vt = (id & 7)*63 + (id >> 3);   // XCD-pinned v-tile
    if (vt >= Vc/16) return;                  // block-uniform early exit
    const int v0 = vt * 16;

    __shared__ float th_l[Bc*51];
    __shared__ float4 uwis[Bc*16];
    const int t = threadIdx.x;
    for (int i = t; i < Bc*Kc; i += 256) {
        int bb = i / Kc, k = i - bb*Kc;
        th_l[bb*51 + k] = exp_m[bidx[bb]*Kc + k] + 0.1f;
    }
    const float2* isir = (const float2*)(ws + WS_ISIR);
    for (int e = t; e < Bc*16; e += 256) {
        int bb = e >> 4, vl = e & 15;
        int gi = bb*Vc + v0 + vl;
        float2 ii = isir[gi];
        float bw = (float)bow[gi];
        uwis[e] = make_float4(bw*ii.x, bw*ii.y, ii.x, 0.f);
    }
    __syncthreads();

    const int lane = t & 63, w = t >> 6;
    const float Sf = (float)(((const int*)ws)[WS_SCNT]);
    float gacc = 0.f;
#pragma unroll
    for (int jj = 0; jj < 4; ++jj) {
        const int vl = w*4 + jj;
        const int v = v0 + vl;
        float PT = 0.f, QT = 0.f, P2 = 0.f;
#pragma unroll 8
        for (int bb = 0; bb < Bc; ++bb) {
            float4 u = uwis[bb*16 + vl];          // full-wave broadcast
            float thv = th_l[bb*51 + lane];
            PT = fmaf(u.x, thv, PT);
            QT = fmaf(u.y, thv, QT);
            P2 = fmaf(u.z, thv, P2);
        }
        if (lane < Kc) {
            int gi = v*Kc + lane;                 // coalesced input reads
            float sv = seeds[gi], en = exp_n[gi], es = exp_s[gi];
            float pk = pi[lane];
            float st = (0.1f + es) / (0.1f*Sf + ws[WS_SSUM + lane]);
            float rt = (0.1f + en) / (0.1f*(float)Vc + ws[WS_NSUM + lane]);
            float sc = sv*st*pk, n1 = sv*rt*(1.f - pk), n2 = (1.f - sv)*rt;
            out[Bc*Kc + gi]         = fmaf(n1, PT, n2*QT);   // temp_exp_n staging
            out[Bc*Kc + Vc*Kc + gi] = sc*PT;                 // temp_exp_s staging
            gacc = fmaf(n1, P2, gacc);
        }
    }
    if (lane < Kc) atomicAdd(&ws[WS_GSRSH + (id & 63)*Kc + lane], gacc);
}

// ---------------- k3: finalize n/s (flat) + m + qz ---------------------------
__global__ __launch_bounds__(256) void k3_fin(
    const float* __restrict__ exp_m, const float* __restrict__ exp_n,
    const float* __restrict__ exp_s, const int* __restrict__ bidx,
    const int* __restrict__ itern_p, float* __restrict__ out,
    float* __restrict__ ws)
{
    const int t = threadIdx.x, blk = blockIdx.x;
    int ii = itern_p[0];
    float itern = (ii >= 0 && ii < 1000000) ? (float)ii : __int_as_float(ii);
    const float rho = 1.f / powf(itern + 5.f, 0.9f);
    const float omr = 1.f - rho;
    const float bC  = (float)(((const int*)ws)[WS_BATCHC]);
    const float rs  = rho * (1e7f / bC);
    float* out_m = out;
    float* out_n = out + Bc*Kc;
    float* out_s = out + Bc*Kc + Vc*Kc;
    const int NB = (Vc*Kc + 255) / 256;     // 1563

    if (blk < NB) {
        __shared__ float ssl[Kc];
        for (int i = t; i < Kc; i += 256) ssl[i] = 0.f;
        __syncthreads();
        int i = blk*256 + t;
        if (i < Vc*Kc) {
            int k = i % Kc;
            out_n[i] = fmaf(omr, exp_n[i], rs*out_n[i]);
            float snew = fmaf(omr, exp_s[i], rs*out_s[i]);
            out_s[i] = snew;
            atomicAdd(&ssl[k], snew);
        }
        __syncthreads();
        if (t < Kc) atomicAdd(&ws[WS_SSNSH + (blk & 31)*Kc + t], ssl[t]);
    } else {
        for (int i = t; i < Bc*Kc; i += 256) {
            int bb = i / Kc, k = i - bb*Kc;
            float th = exp_m[bidx[bb]*Kc + k] + 0.1f;
            out_m[i] = fmaf(omr, th - 0.1f, rho*th*ws[WS_PM + i]);
        }
        if (t == 0) {
            float qz = 0.f;
            for (int s = 0; s < 32; ++s) qz += ws[WS_QZSH + s];
            out[Bc*Kc + 2*Vc*Kc + Kc] = qz;
        }
    }
}

__global__ void k4_pi(const float* __restrict__ ws, float* __restrict__ out) {
    int k = threadIdx.x;
    if (k < Kc) {
        float ssn = 0.f, srs = 0.f;
        for (int s = 0; s < 32; ++s) ssn += ws[WS_SSNSH + s*Kc + k];
        for (int s = 0; s < 64; ++s) srs += ws[WS_GSRSH + s*Kc + k];
        float p = ssn / (ssn + srs + 1e-6f);
        out[Bc*Kc + 2*Vc*Kc + k] = (p > 0.1f) ? p : 0.7f;
    }
}

// ================= Fallback path (round-1 monolith, small ws) ================
__global__ __launch_bounds__(256) void fb_k1(const int* __restrict__ bow,
    const float* __restrict__ seeds, const float* __restrict__ exp_n,
    const float* __restrict__ exp_s, float* __restrict__ ws)
{
    __shared__ float redf[256];
    __shared__ int   redi[256];
    const int t = threadIdx.x, blk = blockIdx.x;
    if (blk < Kc) {
        float sn = 0.f, ss = 0.f;
        for (int v = t; v < Vc; v += 256) {
            sn += exp_n[v*Kc + blk];
            ss += exp_s[v*Kc + blk];
        }
        redf[t] = sn; __syncthreads();
        for (int s = 128; s > 0; s >>= 1) { if (t < s) redf[t] += redf[t+s]; __syncthreads(); }
        if (t == 0) ws[WS_NSUM + blk] = redf[0];
        __syncthreads();
        redf[t] = ss; __syncthreads();
        for (int s = 128; s > 0; s >>= 1) { if (t < s) redf[t] += redf[t+s]; __syncthreads(); }
        if (t == 0) ws[WS_SSUM + blk] = redf[0];
    } else if (blk < Kc + 32) {
        int acc = 0;
        for (int i = (blk - Kc)*256 + t; i < Bc*Vc; i += 32*256) acc += bow[i];
        redi[t] = acc; __syncthreads();
        for (int s = 128; s > 0; s >>= 1) { if (t < s) redi[t] += redi[t+s]; __syncthreads(); }
        if (t == 0) atomicAdd((int*)ws + WS_BATCHC, redi[0]);
    } else {
        int cnt = 0;
        for (int v = (blk - Kc - 32)*256 + t; v < Vc; v += 8*256) {
            const float* row = seeds + v*Kc;
            int any = 0;
            for (int k = 0; k < Kc; ++k) any |= (row[k] != 0.f);
            cnt += any;
        }
        redi[t] = cnt; __syncthreads();
        for (int s = 128; s > 0; s >>= 1) { if (t < s) redi[t] += redi[t+s]; __syncthreads(); }
        if (t == 0) atomicAdd((int*)ws + WS_SCNT, redi[0]);
    }
}

__global__ __launch_bounds__(512) void fb_k2(
    const int* __restrict__ bow, const int* __restrict__ bidx,
    const float* __restrict__ seeds, const float* __restrict__ exp_m,
    const float* __restrict__ exp_n, const float* __restrict__ exp_s,
    const float* __restrict__ pi, float* __restrict__ ws,
    float* __restrict__ out)
{
    float* out_m = out;
    float* out_n = out + Bc*Kc;
    float* out_s = out + Bc*Kc + Vc*Kc;
    __shared__ float lds_m[Bc*Kc];
    __shared__ float lds_theta[Bc*Kc];
    __shared__ float lds_srsum[Kc];
    __shared__ float lds_qz;
    const int t = threadIdx.x;
    for (int i = t; i < Bc*Kc; i += 512) lds_m[i] = 0.f;
    if (t < Kc) lds_srsum[t] = 0.f;
    if (t == 0) lds_qz = 0.f;
    for (int i = t; i < Bc*Kc; i += 512) {
        int b = i / Kc;
        lds_theta[i] = exp_m[bidx[b]*Kc + (i - b*Kc)] + 0.1f;
    }
    __syncthreads();
    const int lane = t & 63, wid = t >> 6;
    const int gw = blockIdx.x*8 + wid, nw = gridDim.x*8;
    const int k = lane;
    const bool kval = (k < Kc);
    const float S_f = (float)(((const int*)ws)[WS_SCNT]);
    float pi_k = 0.f, omp_k = 0.f, sden_inv = 0.f, rden_inv = 0.f;
    if (kval) {
        pi_k = pi[k]; omp_k = 1.f - pi_k;
        sden_inv = 1.f / (0.1f*S_f + ws[WS_SSUM + k]);
        rden_inv = 1.f / (0.1f*(float)Vc + ws[WS_NSUM + k]);
    }
    float acc_sr = 0.f, acc_qz = 0.f;
    for (int v = gw; v < Vc; v += nw) {
        float seeds_vk = 0.f, es = 0.f, en = 0.f;
        if (kval) { seeds_vk = seeds[v*Kc+k]; es = exp_s[v*Kc+k]; en = exp_n[v*Kc+k]; }
        const float st = (0.1f + es)*sden_inv;
        const float rt = (0.1f + en)*rden_inv;
        const bool seed_word = (__ballot(seeds_vk != 0.f) != 0ULL);
        const float bow_lane = (float)bow[lane*Vc + v];
        float acc_n = 0.f, acc_s = 0.f;
        for (int b = 0; b < Bc; ++b) {
            const float bw = __shfl(bow_lane, b);
            if (bw == 0.f) continue;
            const float th = lds_theta[b*Kc + (kval ? k : 0)];
            float ss = seeds_vk*th*st*pi_k;
            float sr = seeds_vk*th*rt*omp_k;
            float rr = (1.f - seeds_vk)*th*rt;
            float ssum = ss + sr, rsum = rr;
            for (int off = 32; off > 0; off >>= 1) {
                ssum += __shfl_xor(ssum, off);
                rsum += __shfl_xor(rsum, off);
            }
            const float inv_s = __builtin_amdgcn_rcpf(ssum + 1e-6f);
            const float inv_r = __builtin_amdgcn_rcpf(rsum + 1e-6f);
            const float ssn = ss*inv_s, srn = sr*inv_s, rrn = rr*inv_r;
            const float g = seed_word ? (pi_k*ssn + omp_k*(srn + rrn)) : rrn;
            acc_n += (srn + rrn)*bw;
            acc_s += ssn*bw;
            acc_sr += srn;
            acc_qz += g*__logf(g + 1e-6f);
            if (kval) atomicAdd(&lds_m[b*Kc + k], g*bw);
        }
        if (kval) { out_n[v*Kc + k] = acc_n; out_s[v*Kc + k] = acc_s; }
    }
    if (kval) atomicAdd(&lds_srsum[k], acc_sr);
    for (int off = 32; off > 0; off >>= 1) acc_qz += __shfl_xor(acc_qz, off);
    if (lane == 0) atomicAdd(&lds_qz, acc_qz);
    __syncthreads();
    for (int i = t; i < Bc*Kc; i += 512) {
        float vtm = lds_m[i];
        if (vtm != 0.f) atomicAdd(&out_m[i], vtm);
    }
    if (t < Kc) atomicAdd(&ws[WS_GSRSH + t], lds_srsum[t]);
    if (t == 0) atomicAdd(&ws[WS_QZ], lds_qz);
}

__global__ __launch_bounds__(256) void fb_k3(
    const float* __restrict__ exp_m, const float* __restrict__ exp_n,
    const float* __restrict__ exp_s, const int* __restrict__ bidx,
    const int* __restrict__ itern_p, float* __restrict__ out,
    float* __restrict__ ws)
{
    const int t = threadIdx.x, blk = blockIdx.x;
    int ii = itern_p[0];
    float itern = (ii >= 0 && ii < 1000000) ? (float)ii : __int_as_float(ii);
    const float rho = 1.f / powf(itern + 5.f, 0.9f);
    const float omr = 1.f - rho;
    const float bC = (float)(((const int*)ws)[WS_BATCHC]);
    const float scale = 1e7f / bC;
    float* out_m = out;
    float* out_n = out + Bc*Kc;
    float* out_s = out + Bc*Kc + Vc*Kc;
    if (blk < Kc) {
        const int k = blk;
        float acc = 0.f;
        for (int v = t; v < Vc; v += 256) {
            int i = v*Kc + k;
            out_n[i] = omr*exp_n[i] + rho*scale*out_n[i];
            float snew = omr*exp_s[i] + rho*scale*out_s[i];
            out_s[i] = snew;
            acc += snew;
        }
        __shared__ float redf[256];
        redf[t] = acc; __syncthreads();
        for (int s = 128; s > 0; s >>= 1) { if (t < s) redf[t] += redf[t+s]; __syncthreads(); }
        if (t == 0) ws[WS_SSNSH + k] = redf[0];
    } else {
        for (int i = t; i < Bc*Kc; i += 256) {
            int b = i / Kc;
            out_m[i] = omr*exp_m[bidx[b]*Kc + (i - b*Kc)] + rho*out_m[i];
        }
        if (t == 0) out[Bc*Kc + 2*Vc*Kc + Kc] = ws[WS_QZ];
    }
}

__global__ void fb_k4(const float* __restrict__ ws, float* __restrict__ out) {
    int k = threadIdx.x;
    if (k < Kc) {
        float ssn = ws[WS_SSNSH + k];
        float srs = ws[WS_GSRSH + k];
        float p = ssn / (ssn + srs + 1e-6f);
        out[Bc*Kc + 2*Vc*Kc + k] = (p > 0.1f) ? p : 0.7f;
    }
}

// =============================================================================
extern "C" void kernel_launch(void* const* d_in, const int* in_sizes, int n_in,
                              void* d_out, int out_size, void* d_ws, size_t ws_size,
                              hipStream_t stream)
{
    const int*   bow    = (const int*)d_in[0];
    const int*   bidx   = (const int*)d_in[1];
    const float* seeds  = (const float*)d_in[2];
    const float* exp_m  = (const float*)d_in[3];
    const float* exp_n  = (const float*)d_in[4];
    const float* exp_s  = (const float*)d_in[5];
    const float* pi     = (const float*)d_in[6];
    const int*   iter_n = (const int*)d_in[7];
    float* out = (float*)d_out;
    float* ws  = (float*)d_ws;

    if (ws_size >= (size_t)WS_END * sizeof(float)) {
        hipMemsetAsync(d_ws, 0, 33280, stream);   // scalars + pm + shards
        k1_pre<<<48, 256, 0, stream>>>(bow, seeds, exp_n, exp_s, ws);
        kA1<<<Vc/64, 256, 0, stream>>>(seeds, exp_n, exp_s, pi, ws);
        kMAIN<<<1024, 256, 0, stream>>>(bow, bidx, exp_m, ws);
        kC<<<504, 256, 0, stream>>>(bow, bidx, exp_m, seeds, exp_n, exp_s, pi, ws, out);
        k3_fin<<<(Vc*Kc + 255)/256 + 1, 256, 0, stream>>>(exp_m, exp_n, exp_s, bidx, iter_n, out, ws);
        k4_pi<<<1, 64, 0, stream>>>(ws, out);
    } else {
        hipMemsetAsync(d_ws, 0, 33280 < ws_size ? 33280 : ws_size, stream);
        hipMemsetAsync(d_out, 0, Bc*Kc*sizeof(float), stream);
        fb_k1<<<Kc + 32 + 8, 256, 0, stream>>>(bow, seeds, exp_n, exp_s, ws);
        fb_k2<<<256, 512, 0, stream>>>(bow, bidx, seeds, exp_m, exp_n, exp_s, pi, ws, out);
        fb_k3<<<Kc + 1, 256, 0, stream>>>(exp_m, exp_n, exp_s, bidx, iter_n, out, ws);
        fb_k4<<<1, 64, 0, stream>>>(ws, out);
    }
}

// Round 5
// 116.646 us; speedup vs baseline: 2.1496x; 1.2937x over previous
//
#include <hip/hip_runtime.h>
#include <math.h>

constexpr int Bc = 64;      // batch
constexpr int Vc = 8000;    // vocab
constexpr int Kc = 50;      // topics

// ws float-offsets (low region zeroed by memset)
#define WS_NSUM   0        // 50  exp_n colsum (atomic)
#define WS_SSUM   50       // 50  exp_s colsum (atomic)
#define WS_GSR    100      // fallback uses
#define WS_QZ     150      // fallback qz
#define WS_BATCHC 151      // batch_C (atomic int)
#define WS_SCNT   152      // seed-word count (atomic int)
#define WS_QZSH   220      // 32 qz shards
#define WS_PM     256      // 64*50 temp_m pre-theta (atomic f32)
#define WS_GSRSH  3456     // 64*50 gamma_sr_sum shards
#define WS_SSNSH  6656     // 32*50 exp_s_sum_new shards
#define WS_SW     8256     // 8000 seed-word flags
#define WS_CD2    16384                    // float4 [k2][v]: (C0,D0,C1,D1)
#define WS_GG2    (WS_CD2 + Vc*Kc*2)       // float4 [k2][v]: (ge0,gf0,ge1,gf1)
#define WS_ISIR   (WS_GG2 + Vc*Kc*2)       // float2 [v][b]: (is, ir)
#define WS_END    (WS_ISIR + 2*Bc*Vc)      // 2640384 floats = 10.56 MB

// ---------------- k1: colsums, batch_C, seed flags ---------------------------
__global__ __launch_bounds__(256) void k1_pre(const int* __restrict__ bow,
    const float* __restrict__ seeds, const float* __restrict__ exp_n,
    const float* __restrict__ exp_s, float* __restrict__ ws)
{
    const int t = threadIdx.x, blk = blockIdx.x;
    if (blk < 32) {
        __shared__ float csn[Kc], css[Kc];
        for (int i = t; i < Kc; i += 256) { csn[i] = 0.f; css[i] = 0.f; }
        __syncthreads();
        for (int i = blk*256 + t; i < Vc*Kc; i += 32*256) {
            int k = i % Kc;
            atomicAdd(&csn[k], exp_n[i]);
            atomicAdd(&css[k], exp_s[i]);
        }
        __syncthreads();
        if (t < Kc) {
            atomicAdd(&ws[WS_NSUM + t], csn[t]);
            atomicAdd(&ws[WS_SSUM + t], css[t]);
        }
    } else if (blk < 40) {
        __shared__ int redi[256];
        int acc = 0;
        for (int i = (blk-32)*256 + t; i < Bc*Vc; i += 8*256) acc += bow[i];
        redi[t] = acc; __syncthreads();
        for (int s = 128; s > 0; s >>= 1) { if (t < s) redi[t] += redi[t+s]; __syncthreads(); }
        if (t == 0) atomicAdd((int*)ws + WS_BATCHC, redi[0]);
    } else {
        __shared__ int redi[256];
        int cnt = 0;
        for (int v = (blk-40)*256 + t; v < Vc; v += 8*256) {
            const float* row = seeds + v*Kc;
            int any = 0;
            for (int k = 0; k < Kc; ++k) any |= (row[k] != 0.f);
            cnt += any;
            ws[WS_SW + v] = any ? 1.f : 0.f;
        }
        redi[t] = cnt; __syncthreads();
        for (int s = 128; s > 0; s >>= 1) { if (t < s) redi[t] += redi[t+s]; __syncthreads(); }
        if (t == 0) atomicAdd((int*)ws + WS_SCNT, redi[0]);
    }
}

// ---------------- kA1: build packed float4 coefficient arrays ----------------
__global__ __launch_bounds__(256) void kA1(const float* __restrict__ seeds,
    const float* __restrict__ exp_n, const float* __restrict__ exp_s,
    const float* __restrict__ pi, float* __restrict__ ws)
{
    __shared__ float tsv[64*51], ten[64*51], tes[64*51];
    const int t = threadIdx.x;
    const int v0 = blockIdx.x * 64;
    for (int i = t; i < 64*Kc; i += 256) {
        int vl = i / Kc, k = i - vl*Kc;
        int gi = (v0 + vl)*Kc + k;           // coalesced reads
        tsv[vl*51 + k] = seeds[gi];
        ten[vl*51 + k] = exp_n[gi];
        tes[vl*51 + k] = exp_s[gi];
    }
    __syncthreads();
    const float Sf = (float)(((const int*)ws)[WS_SCNT]);
    const float musum = 0.1f*Sf, betasum = 0.1f*(float)Vc;
    float4* CD2 = (float4*)(ws + WS_CD2);
    float4* GG2 = (float4*)(ws + WS_GG2);
    for (int i = t; i < 64*(Kc/2); i += 256) {
        int k2 = i >> 6, vl = i & 63;        // k2 wave-uniform, vl consecutive
        float swv = ws[WS_SW + v0 + vl];
        float C[2], D[2], GE[2], GF[2];
#pragma unroll
        for (int h = 0; h < 2; ++h) {
            int k = 2*k2 + h;
            float sv = tsv[vl*51 + k], en = ten[vl*51 + k], es = tes[vl*51 + k];
            float pk = pi[k];
            float st = (0.1f + es) / (musum   + ws[WS_SSUM + k]);
            float rt = (0.1f + en) / (betasum + ws[WS_NSUM + k]);
            float sc = sv*st*pk, n1 = sv*rt*(1.f - pk), n2 = (1.f - sv)*rt;
            C[h] = sc + n1;  D[h] = n2;
            GE[h] = fmaf(pk, sc, (1.f - pk)*n1);
            GF[h] = (swv != 0.f) ? (1.f - pk)*n2 : n2;
        }
        CD2[(size_t)k2*Vc + v0 + vl] = make_float4(C[0], D[0], C[1], D[1]);
        GG2[(size_t)k2*Vc + v0 + vl] = make_float4(GE[0], GF[0], GE[1], GF[1]);
    }
}

// ---------------- kMAIN: wave = v, lane = b ---------------------------------
// Coefficient loads are wave-broadcast (1 line/tx, each (v,k) fetched ONCE
// total); theta + pm live in VGPRs; is/ir stay in registers between passes.
__global__ __launch_bounds__(256) void kMAIN(const int* __restrict__ bow,
    const int* __restrict__ bidx, const float* __restrict__ exp_m,
    float* __restrict__ ws)
{
    const int id = blockIdx.x;
    const int vt = (id & 7)*64 + (id >> 3);   // XCD-pinned v-tile (16 v's)
    if (vt >= Vc/16) return;                  // block-uniform
    const int v0 = vt * 16;

    __shared__ float th_l[64*51];
    __shared__ float pm_l[Bc*Kc];
    __shared__ float bow_l[16*65];
    __shared__ float qz_l;
    const int t = threadIdx.x;
    const int lane = t & 63, w = t >> 6;

    for (int i = t; i < Bc*Kc; i += 256) {
        int b = i / Kc, k = i - b*Kc;
        th_l[b*51 + k] = exp_m[bidx[b]*Kc + k] + 0.1f;   // coalesced
        pm_l[i] = 0.f;
    }
    for (int e = t; e < 16*64; e += 256) {
        int b = e >> 4, vl = e & 15;
        bow_l[vl*65 + b] = (float)bow[b*Vc + v0 + vl];
    }
    if (t == 0) qz_l = 0.f;
    __syncthreads();

    float th[Kc];
#pragma unroll
    for (int k = 0; k < Kc; ++k) th[k] = th_l[lane*51 + k];  // lane = b

    const float4* CD2 = (const float4*)(ws + WS_CD2);
    const float4* GG2 = (const float4*)(ws + WS_GG2);
    float2* isir = (float2*)(ws + WS_ISIR);

    float pm[Kc];
#pragma unroll
    for (int k = 0; k < Kc; ++k) pm[k] = 0.f;
    float qz0 = 0.f, qz1 = 0.f, qz2 = 0.f, qz3 = 0.f;

    for (int i = 0; i < 4; ++i) {
        const int vl = i*4 + w;              // wave owns this v
        const int v = v0 + vl;
        const float bw = bow_l[vl*65 + lane];
        float S = 0.f, S2 = 0.f, R = 0.f, R2 = 0.f;
#pragma unroll
        for (int k2 = 0; k2 < Kc/2; ++k2) {
            float4 cd = CD2[(size_t)k2*Vc + v];      // broadcast load
            S  = fmaf(th[2*k2],   cd.x, S);  R  = fmaf(th[2*k2],   cd.y, R);
            S2 = fmaf(th[2*k2+1], cd.z, S2); R2 = fmaf(th[2*k2+1], cd.w, R2);
        }
        S += S2; R += R2;
        const bool msk = bw > 0.f;
        const float is = msk ? 1.f/(S + 1e-6f) : 0.f;
        const float ir = msk ? 1.f/(R + 1e-6f) : 0.f;
        isir[(size_t)v*Bc + lane] = make_float2(is, ir);   // coalesced 512B
#pragma unroll
        for (int k2 = 0; k2 < Kc/2; ++k2) {
            float4 gg = GG2[(size_t)k2*Vc + v];      // broadcast load
            float t1a = fmaf(gg.x, is, gg.y*ir);
            float t1b = fmaf(gg.z, is, gg.w*ir);
            float ga = th[2*k2]*t1a;
            float gb = th[2*k2+1]*t1b;
            if (k2 & 1) {
                qz2 = fmaf(ga, __logf(ga + 1e-6f), qz2);
                qz3 = fmaf(gb, __logf(gb + 1e-6f), qz3);
            } else {
                qz0 = fmaf(ga, __logf(ga + 1e-6f), qz0);
                qz1 = fmaf(gb, __logf(gb + 1e-6f), qz1);
            }
            pm[2*k2]   = fmaf(bw, t1a, pm[2*k2]);
            pm[2*k2+1] = fmaf(bw, t1b, pm[2*k2+1]);
        }
    }

    // merge pm across the 4 waves (lane owns distinct b per wave -> no atomics)
    for (int ww = 0; ww < 4; ++ww) {
        if (w == ww) {
#pragma unroll
            for (int k = 0; k < Kc; ++k) pm_l[lane*Kc + k] += pm[k];
        }
        __syncthreads();
    }
    float qz = (qz0 + qz1) + (qz2 + qz3);
    for (int off = 32; off; off >>= 1) qz += __shfl_xor(qz, off);
    if (lane == 0) atomicAdd(&qz_l, qz);
    __syncthreads();
    for (int i = t; i < Bc*Kc; i += 256) atomicAdd(&ws[WS_PM + i], pm_l[i]);
    if (t == 0) atomicAdd(&ws[WS_QZSH + (id & 31)], qz_l);
}

// ---------------- kC: temp_n, temp_s, gamma_sr_sum ---------------------------
// 16 v per block (XCD-pinned to match kMAIN's isir locality).
__global__ __launch_bounds__(256) void kC(const int* __restrict__ bow,
    const int* __restrict__ bidx, const float* __restrict__ exp_m,
    const float* __restrict__ seeds, const float* __restrict__ exp_n,
    const float* __restrict__ exp_s, const float* __restrict__ pi,
    float* __restrict__ ws, float* __restrict__ out)
{
    const int id = blockIdx.x;
    const int vt = (id & 7)*63 + (id >> 3);   // XCD-pinned v-tile
    if (vt >= Vc/16) return;                  // block-uniform early exit
    const int v0 = vt * 16;

    __shared__ float th_l[Bc*51];
    __shared__ float4 uwis[16*Bc];
    const int t = threadIdx.x;
    for (int i = t; i < Bc*Kc; i += 256) {
        int bb = i / Kc, k = i - bb*Kc;
        th_l[bb*51 + k] = exp_m[bidx[bb]*Kc + k] + 0.1f;
    }
    const float2* isir = (const float2*)(ws + WS_ISIR);
    for (int e = t; e < 16*Bc; e += 256) {
        int vl = e >> 6, bb = e & 63;
        float2 ii = isir[(size_t)(v0 + vl)*Bc + bb];   // coalesced
        float bw = (float)bow[bb*Vc + v0 + vl];
        uwis[vl*Bc + bb] = make_float4(bw*ii.x, bw*ii.y, ii.x, 0.f);
    }
    __syncthreads();

    const int lane = t & 63, w = t >> 6;
    const float Sf = (float)(((const int*)ws)[WS_SCNT]);
    float gacc = 0.f;
#pragma unroll
    for (int jj = 0; jj < 4; ++jj) {
        const int vl = w*4 + jj;
        const int v = v0 + vl;
        float PT = 0.f, QT = 0.f, P2 = 0.f;
#pragma unroll 8
        for (int bb = 0; bb < Bc; ++bb) {
            float4 u = uwis[vl*Bc + bb];          // full-wave broadcast
            float thv = th_l[bb*51 + lane];
            PT = fmaf(u.x, thv, PT);
            QT = fmaf(u.y, thv, QT);
            P2 = fmaf(u.z, thv, P2);
        }
        if (lane < Kc) {
            int gi = v*Kc + lane;                 // coalesced input reads
            float sv = seeds[gi], en = exp_n[gi], es = exp_s[gi];
            float pk = pi[lane];
            float st = (0.1f + es) / (0.1f*Sf + ws[WS_SSUM + lane]);
            float rt = (0.1f + en) / (0.1f*(float)Vc + ws[WS_NSUM + lane]);
            float sc = sv*st*pk, n1 = sv*rt*(1.f - pk), n2 = (1.f - sv)*rt;
            out[Bc*Kc + gi]         = fmaf(n1, PT, n2*QT);   // temp_exp_n staging
            out[Bc*Kc + Vc*Kc + gi] = sc*PT;                 // temp_exp_s staging
            gacc = fmaf(n1, P2, gacc);
        }
    }
    if (lane < Kc) atomicAdd(&ws[WS_GSRSH + (id & 63)*Kc + lane], gacc);
}

// ---------------- k3: finalize n/s (flat) + m + qz ---------------------------
__global__ __launch_bounds__(256) void k3_fin(
    const float* __restrict__ exp_m, const float* __restrict__ exp_n,
    const float* __restrict__ exp_s, const int* __restrict__ bidx,
    const int* __restrict__ itern_p, float* __restrict__ out,
    float* __restrict__ ws)
{
    const int t = threadIdx.x, blk = blockIdx.x;
    int ii = itern_p[0];
    float itern = (ii >= 0 && ii < 1000000) ? (float)ii : __int_as_float(ii);
    const float rho = 1.f / powf(itern + 5.f, 0.9f);
    const float omr = 1.f - rho;
    const float bC  = (float)(((const int*)ws)[WS_BATCHC]);
    const float rs  = rho * (1e7f / bC);
    float* out_m = out;
    float* out_n = out + Bc*Kc;
    float* out_s = out + Bc*Kc + Vc*Kc;
    const int NB = (Vc*Kc + 255) / 256;     // 1563

    if (blk < NB) {
        __shared__ float ssl[Kc];
        for (int i = t; i < Kc; i += 256) ssl[i] = 0.f;
        __syncthreads();
        int i = blk*256 + t;
        if (i < Vc*Kc) {
            int k = i % Kc;
            out_n[i] = fmaf(omr, exp_n[i], rs*out_n[i]);
            float snew = fmaf(omr, exp_s[i], rs*out_s[i]);
            out_s[i] = snew;
            atomicAdd(&ssl[k], snew);
        }
        __syncthreads();
        if (t < Kc) atomicAdd(&ws[WS_SSNSH + (blk & 31)*Kc + t], ssl[t]);
    } else {
        for (int i = t; i < Bc*Kc; i += 256) {
            int bb = i / Kc, k = i - bb*Kc;
            float th = exp_m[bidx[bb]*Kc + k] + 0.1f;
            out_m[i] = fmaf(omr, th - 0.1f, rho*th*ws[WS_PM + i]);
        }
        if (t == 0) {
            float qz = 0.f;
            for (int s = 0; s < 32; ++s) qz += ws[WS_QZSH + s];
            out[Bc*Kc + 2*Vc*Kc + Kc] = qz;
        }
    }
}

__global__ void k4_pi(const float* __restrict__ ws, float* __restrict__ out) {
    int k = threadIdx.x;
    if (k < Kc) {
        float ssn = 0.f, srs = 0.f;
        for (int s = 0; s < 32; ++s) ssn += ws[WS_SSNSH + s*Kc + k];
        for (int s = 0; s < 64; ++s) srs += ws[WS_GSRSH + s*Kc + k];
        float p = ssn / (ssn + srs + 1e-6f);
        out[Bc*Kc + 2*Vc*Kc + k] = (p > 0.1f) ? p : 0.7f;
    }
}

// ================= Fallback path (round-1 monolith, small ws) ================
__global__ __launch_bounds__(256) void fb_k1(const int* __restrict__ bow,
    const float* __restrict__ seeds, const float* __restrict__ exp_n,
    const float* __restrict__ exp_s, float* __restrict__ ws)
{
    __shared__ float redf[256];
    __shared__ int   redi[256];
    const int t = threadIdx.x, blk = blockIdx.x;
    if (blk < Kc) {
        float sn = 0.f, ss = 0.f;
        for (int v = t; v < Vc; v += 256) {
            sn += exp_n[v*Kc + blk];
            ss += exp_s[v*Kc + blk];
        }
        redf[t] = sn; __syncthreads();
        for (int s = 128; s > 0; s >>= 1) { if (t < s) redf[t] += redf[t+s]; __syncthreads(); }
        if (t == 0) ws[WS_NSUM + blk] = redf[0];
        __syncthreads();
        redf[t] = ss; __syncthreads();
        for (int s = 128; s > 0; s >>= 1) { if (t < s) redf[t] += redf[t+s]; __syncthreads(); }
        if (t == 0) ws[WS_SSUM + blk] = redf[0];
    } else if (blk < Kc + 32) {
        int acc = 0;
        for (int i = (blk - Kc)*256 + t; i < Bc*Vc; i += 32*256) acc += bow[i];
        redi[t] = acc; __syncthreads();
        for (int s = 128; s > 0; s >>= 1) { if (t < s) redi[t] += redi[t+s]; __syncthreads(); }
        if (t == 0) atomicAdd((int*)ws + WS_BATCHC, redi[0]);
    } else {
        int cnt = 0;
        for (int v = (blk - Kc - 32)*256 + t; v < Vc; v += 8*256) {
            const float* row = seeds + v*Kc;
            int any = 0;
            for (int k = 0; k < Kc; ++k) any |= (row[k] != 0.f);
            cnt += any;
        }
        redi[t] = cnt; __syncthreads();
        for (int s = 128; s > 0; s >>= 1) { if (t < s) redi[t] += redi[t+s]; __syncthreads(); }
        if (t == 0) atomicAdd((int*)ws + WS_SCNT, redi[0]);
    }
}

__global__ __launch_bounds__(512) void fb_k2(
    const int* __restrict__ bow, const int* __restrict__ bidx,
    const float* __restrict__ seeds, const float* __restrict__ exp_m,
    const float* __restrict__ exp_n, const float* __restrict__ exp_s,
    const float* __restrict__ pi, float* __restrict__ ws,
    float* __restrict__ out)
{
    float* out_m = out;
    float* out_n = out + Bc*Kc;
    float* out_s = out + Bc*Kc + Vc*Kc;
    __shared__ float lds_m[Bc*Kc];
    __shared__ float lds_theta[Bc*Kc];
    __shared__ float lds_srsum[Kc];
    __shared__ float lds_qz;
    const int t = threadIdx.x;
    for (int i = t; i < Bc*Kc; i += 512) lds_m[i] = 0.f;
    if (t < Kc) lds_srsum[t] = 0.f;
    if (t == 0) lds_qz = 0.f;
    for (int i = t; i < Bc*Kc; i += 512) {
        int b = i / Kc;
        lds_theta[i] = exp_m[bidx[b]*Kc + (i - b*Kc)] + 0.1f;
    }
    __syncthreads();
    const int lane = t & 63, wid = t >> 6;
    const int gw = blockIdx.x*8 + wid, nw = gridDim.x*8;
    const int k = lane;
    const bool kval = (k < Kc);
    const float S_f = (float)(((const int*)ws)[WS_SCNT]);
    float pi_k = 0.f, omp_k = 0.f, sden_inv = 0.f, rden_inv = 0.f;
    if (kval) {
        pi_k = pi[k]; omp_k = 1.f - pi_k;
        sden_inv = 1.f / (0.1f*S_f + ws[WS_SSUM + k]);
        rden_inv = 1.f / (0.1f*(float)Vc + ws[WS_NSUM + k]);
    }
    float acc_sr = 0.f, acc_qz = 0.f;
    for (int v = gw; v < Vc; v += nw) {
        float seeds_vk = 0.f, es = 0.f, en = 0.f;
        if (kval) { seeds_vk = seeds[v*Kc+k]; es = exp_s[v*Kc+k]; en = exp_n[v*Kc+k]; }
        const float st = (0.1f + es)*sden_inv;
        const float rt = (0.1f + en)*rden_inv;
        const bool seed_word = (__ballot(seeds_vk != 0.f) != 0ULL);
        const float bow_lane = (float)bow[lane*Vc + v];
        float acc_n = 0.f, acc_s = 0.f;
        for (int b = 0; b < Bc; ++b) {
            const float bw = __shfl(bow_lane, b);
            if (bw == 0.f) continue;
            const float th = lds_theta[b*Kc + (kval ? k : 0)];
            float ss = seeds_vk*th*st*pi_k;
            float sr = seeds_vk*th*rt*omp_k;
            float rr = (1.f - seeds_vk)*th*rt;
            float ssum = ss + sr, rsum = rr;
            for (int off = 32; off > 0; off >>= 1) {
                ssum += __shfl_xor(ssum, off);
                rsum += __shfl_xor(rsum, off);
            }
            const float inv_s = __builtin_amdgcn_rcpf(ssum + 1e-6f);
            const float inv_r = __builtin_amdgcn_rcpf(rsum + 1e-6f);
            const float ssn = ss*inv_s, srn = sr*inv_s, rrn = rr*inv_r;
            const float g = seed_word ? (pi_k*ssn + omp_k*(srn + rrn)) : rrn;
            acc_n += (srn + rrn)*bw;
            acc_s += ssn*bw;
            acc_sr += srn;
            acc_qz += g*__logf(g + 1e-6f);
            if (kval) atomicAdd(&lds_m[b*Kc + k], g*bw);
        }
        if (kval) { out_n[v*Kc + k] = acc_n; out_s[v*Kc + k] = acc_s; }
    }
    if (kval) atomicAdd(&lds_srsum[k], acc_sr);
    for (int off = 32; off > 0; off >>= 1) acc_qz += __shfl_xor(acc_qz, off);
    if (lane == 0) atomicAdd(&lds_qz, acc_qz);
    __syncthreads();
    for (int i = t; i < Bc*Kc; i += 512) {
        float vtm = lds_m[i];
        if (vtm != 0.f) atomicAdd(&out_m[i], vtm);
    }
    if (t < Kc) atomicAdd(&ws[WS_GSRSH + t], lds_srsum[t]);
    if (t == 0) atomicAdd(&ws[WS_QZ], lds_qz);
}

__global__ __launch_bounds__(256) void fb_k3(
    const float* __restrict__ exp_m, const float* __restrict__ exp_n,
    const float* __restrict__ exp_s, const int* __restrict__ bidx,
    const int* __restrict__ itern_p, float* __restrict__ out,
    float* __restrict__ ws)
{
    const int t = threadIdx.x, blk = blockIdx.x;
    int ii = itern_p[0];
    float itern = (ii >= 0 && ii < 1000000) ? (float)ii : __int_as_float(ii);
    const float rho = 1.f / powf(itern + 5.f, 0.9f);
    const float omr = 1.f - rho;
    const float bC = (float)(((const int*)ws)[WS_BATCHC]);
    const float scale = 1e7f / bC;
    float* out_m = out;
    float* out_n = out + Bc*Kc;
    float* out_s = out + Bc*Kc + Vc*Kc;
    if (blk < Kc) {
        const int k = blk;
        float acc = 0.f;
        for (int v = t; v < Vc; v += 256) {
            int i = v*Kc + k;
            out_n[i] = omr*exp_n[i] + rho*scale*out_n[i];
            float snew = omr*exp_s[i] + rho*scale*out_s[i];
            out_s[i] = snew;
            acc += snew;
        }
        __shared__ float redf[256];
        redf[t] = acc; __syncthreads();
        for (int s = 128; s > 0; s >>= 1) { if (t < s) redf[t] += redf[t+s]; __syncthreads(); }
        if (t == 0) ws[WS_SSNSH + k] = redf[0];
    } else {
        for (int i = t; i < Bc*Kc; i += 256) {
            int b = i / Kc;
            out_m[i] = omr*exp_m[bidx[b]*Kc + (i - b*Kc)] + rho*out_m[i];
        }
        if (t == 0) out[Bc*Kc + 2*Vc*Kc + Kc] = ws[WS_QZ];
    }
}

__global__ void fb_k4(const float* __restrict__ ws, float* __restrict__ out) {
    int k = threadIdx.x;
    if (k < Kc) {
        float ssn = ws[WS_SSNSH + k];
        float srs = ws[WS_GSRSH + k];
        float p = ssn / (ssn + srs + 1e-6f);
        out[Bc*Kc + 2*Vc*Kc + k] = (p > 0.1f) ? p : 0.7f;
    }
}

// =============================================================================
extern "C" void kernel_launch(void* const* d_in, const int* in_sizes, int n_in,
                              void* d_out, int out_size, void* d_ws, size_t ws_size,
                              hipStream_t stream)
{
    const int*   bow    = (const int*)d_in[0];
    const int*   bidx   = (const int*)d_in[1];
    const float* seeds  = (const float*)d_in[2];
    const float* exp_m  = (const float*)d_in[3];
    const float* exp_n  = (const float*)d_in[4];
    const float* exp_s  = (const float*)d_in[5];
    const float* pi     = (const float*)d_in[6];
    const int*   iter_n = (const int*)d_in[7];
    float* out = (float*)d_out;
    float* ws  = (float*)d_ws;

    if (ws_size >= (size_t)WS_END * sizeof(float)) {
        hipMemsetAsync(d_ws, 0, 33280, stream);   // scalars + pm + shards
        k1_pre<<<48, 256, 0, stream>>>(bow, seeds, exp_n, exp_s, ws);
        kA1<<<Vc/64, 256, 0, stream>>>(seeds, exp_n, exp_s, pi, ws);
        kMAIN<<<512, 256, 0, stream>>>(bow, bidx, exp_m, ws);
        kC<<<504, 256, 0, stream>>>(bow, bidx, exp_m, seeds, exp_n, exp_s, pi, ws, out);
        k3_fin<<<(Vc*Kc + 255)/256 + 1, 256, 0, stream>>>(exp_m, exp_n, exp_s, bidx, iter_n, out, ws);
        k4_pi<<<1, 64, 0, stream>>>(ws, out);
    } else {
        hipMemsetAsync(d_ws, 0, 33280 < ws_size ? 33280 : ws_size, stream);
        hipMemsetAsync(d_out, 0, Bc*Kc*sizeof(float), stream);
        fb_k1<<<Kc + 32 + 8, 256, 0, stream>>>(bow, seeds, exp_n, exp_s, ws);
        fb_k2<<<256, 512, 0, stream>>>(bow, bidx, seeds, exp_m, exp_n, exp_s, pi, ws, out);
        fb_k3<<<Kc + 1, 256, 0, stream>>>(exp_m, exp_n, exp_s, bidx, iter_n, out, ws);
        fb_k4<<<1, 64, 0, stream>>>(ws, out);
    }
}